// Round 7
// baseline (249.863 us; speedup 1.0000x reference)
//
#include <hip/hip_runtime.h>
#include <stdint.h>

// Problem constants
#define B_  16
#define C_  256
#define H_  64
#define W_  64
#define P_  4096      // H*W
#define E_  8
#define HP_ 66        // padded spatial (64 + 2)

typedef __bf16 bf16x8 __attribute__((ext_vector_type(8)));
typedef float  f32x4  __attribute__((ext_vector_type(4)));

// ---------- helpers ----------
__device__ __forceinline__ unsigned short f2bf(float f) {
    union { float f; unsigned int u; } v; v.f = f;
    unsigned int u = v.u;
    unsigned int r = (u + 0x7fffu + ((u >> 16) & 1u)) >> 16;  // RNE
    return (unsigned short)r;
}

__device__ __forceinline__ void async_load16(const void* g, void* l) {
    __builtin_amdgcn_global_load_lds(
        (const __attribute__((address_space(1))) void*)g,
        (__attribute__((address_space(3))) void*)l, 16, 0, 0);
}

// ---------- k_xpose: Xp[b][h+1][w+1][c] = bf16(x[b][c][h][w]) + fused channel-sum
//            + fused pad-border zeroing (blocks 0..519 also zero a border slice) ----------
__global__ void k_xpose(const float* __restrict__ x, unsigned short* __restrict__ Xp,
                        float* __restrict__ xsum) {
    const int bid = blockIdx.x;       // 16 * 64 * 4
    const int tid = threadIdx.x;

    // Fused border zeroing (was k_border): disjoint from interior writes below.
    if (bid < 520) {
        const int gid = bid * 256 + tid;               // 0..133119
        const int pix = gid >> 5;                      // 0..4159 (16*260)
        const int chunk = gid & 31;
        const int bb = pix / 260;
        const int j = pix - bb * 260;
        int h, w;
        if (j < 66)       { h = 0;  w = j; }
        else if (j < 132) { h = 65; w = j - 66; }
        else { int jj = j - 132; h = 1 + (jj & 63); w = (jj < 64) ? 0 : 65; }
        const uint4 z = {0u, 0u, 0u, 0u};
        *(uint4*)(Xp + ((size_t)((bb * HP_ + h) * HP_ + w) << 8) + chunk * 8) = z;
    }

    const int b  = bid >> 8;
    const int h  = (bid >> 2) & 63;
    const int cg = bid & 3;
    const int c0 = cg << 6;
    __shared__ float tile[64][65];
    {
        const int ci = tid >> 2, wseg = tid & 3;
        const float* src = x + ((size_t)(b * 256 + c0 + ci) << 12) + (h << 6) + wseg * 16;
        float s = 0.f;
#pragma unroll
        for (int i = 0; i < 4; ++i) {
            float4 v = *(const float4*)(src + i * 4);
            tile[ci][wseg * 16 + i * 4 + 0] = v.x;
            tile[ci][wseg * 16 + i * 4 + 1] = v.y;
            tile[ci][wseg * 16 + i * 4 + 2] = v.z;
            tile[ci][wseg * 16 + i * 4 + 3] = v.w;
            s += v.x + v.y + v.z + v.w;
        }
        // reduce the 4 wseg lanes (consecutive) and add to channel sum
        s += __shfl_down(s, 1, 64);
        s += __shfl_down(s, 2, 64);
        if ((tid & 3) == 0) atomicAdd(&xsum[b * 256 + c0 + ci], s);
    }
    __syncthreads();
    {
        const int w = tid >> 2, cs = tid & 3;
        unsigned short ov[16] __attribute__((aligned(16)));
#pragma unroll
        for (int k = 0; k < 16; ++k) ov[k] = f2bf(tile[cs * 16 + k][w]);
        unsigned short* dst = Xp + ((size_t)((b * HP_ + h + 1) * HP_ + (w + 1)) << 8) + c0 + cs * 16;
        ((uint4*)dst)[0] = ((const uint4*)ov)[0];
        ((uint4*)dst)[1] = ((const uint4*)ov)[1];
    }
}

// ---------- k_mix: mix[b][e] = softmax_e(dense(conv_w @ xmean + cb) + db) ----------
__global__ void k_mix(const float* __restrict__ xsum,
                      const float* __restrict__ cw, const float* __restrict__ cb,
                      const float* __restrict__ dw, const float* __restrict__ db,
                      float* __restrict__ mix) {
    const int b = blockIdx.x, tid = threadIdx.x;
    __shared__ __align__(16) float sxm[256];
    __shared__ __align__(16) float spool[256];
    __shared__ float sl[8];
    sxm[tid] = xsum[b * 256 + tid] * (1.0f / P_);
    __syncthreads();
    {
        float a = cb[tid];
        const float4* cwr = (const float4*)(cw + (size_t)tid * 256);
        const float4* xv4 = (const float4*)sxm;
#pragma unroll 8
        for (int c = 0; c < 64; ++c) {
            const float4 wv = cwr[c];
            const float4 xv = xv4[c];
            a += wv.x * xv.x + wv.y * xv.y + wv.z * xv.z + wv.w * xv.w;
        }
        spool[tid] = a;
    }
    __syncthreads();
    if (tid < 64) {
        const int e = tid >> 3, dl = tid & 7;
        float part = 0.f;
#pragma unroll 4
        for (int d = dl; d < 256; d += 8) part += dw[e * 256 + d] * spool[d];
        part += __shfl_down(part, 4, 64);
        part += __shfl_down(part, 2, 64);
        part += __shfl_down(part, 1, 64);
        if (dl == 0) sl[e] = part + db[e];
    }
    __syncthreads();
    if (tid < 8) {
        float m = sl[0];
        for (int e = 1; e < 8; ++e) m = fmaxf(m, sl[e]);
        float den = 0.f;
        for (int e = 0; e < 8; ++e) den += __expf(sl[e] - m);
        mix[b * 8 + tid] = __expf(sl[tid] - m) / den;
    }
}

// ---------- k_mixkern: Wg[b][o][t][ic] = bf16( sum_e mix[b][e] * KE[e][o][ic][t] ) ----------
__global__ void k_mixkern(const float* __restrict__ KE, const float* __restrict__ mix,
                          unsigned short* __restrict__ Wg) {
    const int o    = blockIdx.x >> 1;
    const int half = blockIdx.x & 1;
    const int ic0  = half << 7;
    const int tid  = threadIdx.x;
    __shared__ __align__(16) float s[8][1152];     // 36.9 KB
    __shared__ float smix[128];
    if (tid < 128) smix[tid] = mix[tid];
#pragma unroll
    for (int e = 0; e < 8; ++e) {
        const float4* src = (const float4*)(KE + (size_t)(e * 256 + o) * 2304 + ic0 * 9);
        float4* dst = (float4*)s[e];
        dst[tid] = src[tid];                         // float4 0..255
        if (tid < 32) dst[256 + tid] = src[256 + tid];  // float4 256..287 (= 1152 floats)
    }
    __syncthreads();
    const int icl = tid & 127;
    const int b0  = (tid >> 7) << 3;     // 0 or 8
#pragma unroll
    for (int t = 0; t < 9; ++t) {
        float v[8];
#pragma unroll
        for (int e = 0; e < 8; ++e) v[e] = s[e][icl * 9 + t];
#pragma unroll
        for (int bb = 0; bb < 8; ++bb) {
            const int b = b0 + bb;
            float acc = 0.f;
#pragma unroll
            for (int e = 0; e < 8; ++e) acc += smix[b * 8 + e] * v[e];
            Wg[((size_t)(b * 256 + o) * 9 + t) * 256 + ic0 + icl] = f2bf(acc);
        }
    }
}

// ---------- k_gemm: 256x256-tile 8-wave, 2-window-per-iter, dynamic-overlap GEMM ----------
// Round-7 change: de-serialize LDS-read pipe vs MFMA pipe.
//  (a) NO explicit lgkmcnt(0): af/bv are plain C++ LDS loads; compiler emits
//      fine-grained counted lgkmcnt per consumer -> reads drain UNDER the MFMA burst.
//  (b) ONE barrier per parity window (2/iter, was 4): within a window slots are
//      read-only, so kk0/kk1 need no cross-wave sync; waves desync dynamically and
//      one wave's ds_reads overlap another's MFMA (m114 pipe co-scheduling).
// Window = { reads kk0; stage-issue; 32 MFMA; reads kk1; 32 MFMA; vmcnt(0); s_barrier }.
// Ledger (L0=A-even L1=A-odd L2=B-even L3=B-odd), iter i, sE=2i, sO=2i+1:
//   even window: reads L0,L2; stages A(sO)->L1, B(sO)->L3.
//   odd  window: reads L1,L3; stages A(sE+2)->L0, B(sE+2)->L2 (pf-guarded).
// Slot-write safety: each window ENDS with MFMA that consumed all its reads, so
// all reads of a slot are COMPLETE before any wave passes the barrier and the
// next window's stages (issued post-barrier, landing >=HBM-latency later) touch it.
// vmcnt(0) at window end drains that window's 8 stages; cover = 2 MFMA bursts.
__global__ __launch_bounds__(512, 2) void k_gemm(const unsigned short* __restrict__ Wg,
                                                 const unsigned short* __restrict__ Xp,
                                                 float* __restrict__ out) {
    __shared__ __align__(16) unsigned short L[4][16384];   // 128 KB
    const int tid = threadIdx.x;
    const int bid = blockIdx.x;
    const int xcd = bid & 7;
    const int g   = bid >> 3;            // 0..31
    const int b   = xcd + ((g >> 4) << 3);   // samples {xcd, xcd+8} share one XCD L2
    const int tile = g & 15;
    const int h0  = tile << 2;

    const int wid  = tid >> 6;           // 0..7
    const int lane = tid & 63;
    const int wm   = wid >> 2;           // 0..1: o-half (128 rows)
    const int wn   = wid & 3;            // 0..3: pixel row (64 pixels)
    const int ql   = lane & 15;
    const int quad = lane >> 4;
    const int sw   = ql & 7;             // read-side swizzle key (= row&7)

    const int srow = tid >> 3;           // 0..63
    const int csrc = (tid & 7) ^ (srow & 7);   // global chunk for this thread's LDS slot

    f32x4 acc[8][4];
#pragma unroll
    for (int i = 0; i < 8; ++i)
#pragma unroll
        for (int j = 0; j < 4; ++j) acc[i][j] = (f32x4)0.0f;

    // Stage full A-tile (256 o x 64 k) of K-tile s into L[P]. 4 x 16B per thread.
    auto stageA = [&](int s, int P) {
        const int t = s >> 2, kc = s & 3;
        const unsigned short* ga = Wg + ((size_t)(b * 256 + srow) * 9 + t) * 256
                                   + kc * 64 + csrc * 8;
#pragma unroll
        for (int j = 0; j < 4; ++j)
            async_load16(ga + (size_t)j * 64 * 9 * 256, (char*)L[P] + tid * 16 + j * 8192);
    };
    // Stage full B-tile (256 pixels x 64 k): row = srow + 64j -> pr=j, w=srow.
    auto stageB = [&](int s, int P) {
        const int t = s >> 2, kc = s & 3;
        const int kh = t / 3, kw = t - kh * 3;
#pragma unroll
        for (int j = 0; j < 4; ++j)
            async_load16(Xp + (((size_t)((b * HP_ + h0 + j + kh) * HP_ + (srow + kw))) << 8)
                             + kc * 64 + csrc * 8,
                         (char*)L[2 + P] + tid * 16 + j * 8192);
    };

    bf16x8 af0[4], af1[4], bv[4];

    // Load the 12 fragments for sub-step KK from slots AP/BP (plain C++ loads:
    // compiler tracks deps and emits counted lgkmcnt -> overlaps with MFMA).
#define RDF(AP, BP, KK)                                                            \
    do {                                                                           \
        _Pragma("unroll")                                                          \
        for (int r_ = 0; r_ < 4; ++r_)                                             \
            af0[r_] = *(const bf16x8*)((const char*)L[AP]                          \
                      + (wm * 128 + r_ * 16 + ql) * 128                            \
                      + (((((KK) << 2) | quad) ^ sw) << 4));                       \
        _Pragma("unroll")                                                          \
        for (int r_ = 0; r_ < 4; ++r_)                                             \
            af1[r_] = *(const bf16x8*)((const char*)L[AP]                          \
                      + (wm * 128 + 64 + r_ * 16 + ql) * 128                       \
                      + (((((KK) << 2) | quad) ^ sw) << 4));                       \
        _Pragma("unroll")                                                          \
        for (int r_ = 0; r_ < 4; ++r_)                                             \
            bv[r_] = *(const bf16x8*)((const char*)L[BP]                           \
                     + (wn * 64 + r_ * 16 + ql) * 128                              \
                     + (((((KK) << 2) | quad) ^ sw) << 4));                        \
    } while (0)

#define MFMAS()                                                                    \
    do {                                                                           \
        __builtin_amdgcn_s_setprio(1);                                             \
        _Pragma("unroll")                                                          \
        for (int r_ = 0; r_ < 4; ++r_)                                             \
            _Pragma("unroll")                                                      \
            for (int n_ = 0; n_ < 4; ++n_)                                         \
                acc[r_][n_] = __builtin_amdgcn_mfma_f32_16x16x32_bf16(             \
                    af0[r_], bv[n_], acc[r_][n_], 0, 0, 0);                        \
        _Pragma("unroll")                                                          \
        for (int r_ = 0; r_ < 4; ++r_)                                             \
            _Pragma("unroll")                                                      \
            for (int n_ = 0; n_ < 4; ++n_)                                         \
                acc[4 + r_][n_] = __builtin_amdgcn_mfma_f32_16x16x32_bf16(         \
                    af1[r_], bv[n_], acc[4 + r_][n_], 0, 0, 0);                    \
        __builtin_amdgcn_s_setprio(0);                                             \
    } while (0)

    // Prologue: A(0)->L[0], B(0)->L[2]; drain; barrier.
    stageA(0, 0); stageB(0, 0);
    asm volatile("s_waitcnt vmcnt(0)" ::: "memory");
    asm volatile("s_barrier" ::: "memory");

    for (int i = 0; i < 18; ++i) {
        const int sE = 2 * i;
        const int sO = sE + 1;
        const bool pf = (i < 17);
        // ---- even window (reads L0,L2; stages -> L1,L3) ----
        RDF(0, 2, 0);
        stageA(sO, 1); stageB(sO, 1);
        MFMAS();
        RDF(0, 2, 1);
        MFMAS();
        asm volatile("s_waitcnt vmcnt(0)" ::: "memory");
        asm volatile("s_barrier" ::: "memory");
        // ---- odd window (reads L1,L3; stages -> L0,L2) ----
        RDF(1, 3, 0);
        if (pf) { stageA(sE + 2, 0); stageB(sE + 2, 0); }
        MFMAS();
        RDF(1, 3, 1);
        MFMAS();
        if (pf) { asm volatile("s_waitcnt vmcnt(0)" ::: "memory"); }
        asm volatile("s_barrier" ::: "memory");
    }
#undef RDF
#undef MFMAS

    // Epilogue: C/D layout col=lane&15 (pixel), row=quad*4+reg (o)
#pragma unroll
    for (int m = 0; m < 8; ++m) {
        const int mh = m >> 2, mr = m & 3;           // acc index -> o offset
        const int o = wm * 128 + mh * 64 + mr * 16 + quad * 4;
#pragma unroll
        for (int n = 0; n < 4; ++n) {
            const int w = n * 16 + ql;
            float* po = out + ((size_t)(b * 256 + o) << 12) + ((h0 + wn) << 6) + w;
#pragma unroll
            for (int r = 0; r < 4; ++r) po[(size_t)r << 12] = acc[mh * 4 + mr][n][r];
        }
    }
}

// ---------- launch ----------
extern "C" void kernel_launch(void* const* d_in, const int* in_sizes, int n_in,
                              void* d_out, int out_size, void* d_ws, size_t ws_size,
                              hipStream_t stream) {
    const float* x  = (const float*)d_in[0];
    const float* KE = (const float*)d_in[1];
    const float* cw = (const float*)d_in[2];
    const float* cb = (const float*)d_in[3];
    const float* dw = (const float*)d_in[4];
    const float* db = (const float*)d_in[5];
    float* out = (float*)d_out;

    char* ws = (char*)d_ws;
    float* xsum           = (float*)(ws + 0);            // 16*256*4    = 16 KB
    float* mix            = (float*)(ws + 16384);        // 16*8*4      = 512 B
    unsigned short* Wg    = (unsigned short*)(ws + 32768);            // 18.87 MB
    unsigned short* Xp    = (unsigned short*)(ws + 32768 + 18874368); // 35.68 MB

    hipMemsetAsync(xsum, 0, B_ * C_ * sizeof(float), stream);
    k_xpose  <<<dim3(B_ * H_ * 4),    dim3(256), 0, stream>>>(x, Xp, xsum);
    k_mix    <<<dim3(B_),             dim3(256), 0, stream>>>(xsum, cw, cb, dw, db, mix);
    k_mixkern<<<dim3(C_ * 2),         dim3(256), 0, stream>>>(KE, mix, Wg);
    k_gemm   <<<dim3(256),            dim3(512), 0, stream>>>(Wg, Xp, out);
}

// Round 8
// 246.411 us; speedup vs baseline: 1.0140x; 1.0140x over previous
//
#include <hip/hip_runtime.h>
#include <stdint.h>

// Problem constants
#define B_  16
#define C_  256
#define H_  64
#define W_  64
#define P_  4096      // H*W
#define E_  8
#define HP_ 66        // padded spatial (64 + 2)

typedef __bf16 bf16x8 __attribute__((ext_vector_type(8)));
typedef float  f32x4  __attribute__((ext_vector_type(4)));

// ---------- helpers ----------
__device__ __forceinline__ unsigned short f2bf(float f) {
    union { float f; unsigned int u; } v; v.f = f;
    unsigned int u = v.u;
    unsigned int r = (u + 0x7fffu + ((u >> 16) & 1u)) >> 16;  // RNE
    return (unsigned short)r;
}

__device__ __forceinline__ void async_load16(const void* g, void* l) {
    __builtin_amdgcn_global_load_lds(
        (const __attribute__((address_space(1))) void*)g,
        (__attribute__((address_space(3))) void*)l, 16, 0, 0);
}

// ---------- k_xpose: Xp[b][h+1][w+1][c] = bf16(x[b][c][h][w]) + fused channel-sum
//            + fused pad-border zeroing (blocks 0..519 also zero a border slice) ----------
__global__ void k_xpose(const float* __restrict__ x, unsigned short* __restrict__ Xp,
                        float* __restrict__ xsum) {
    const int bid = blockIdx.x;       // 16 * 64 * 4
    const int tid = threadIdx.x;

    // Fused border zeroing (was k_border): disjoint from interior writes below.
    if (bid < 520) {
        const int gid = bid * 256 + tid;               // 0..133119
        const int pix = gid >> 5;                      // 0..4159 (16*260)
        const int chunk = gid & 31;
        const int bb = pix / 260;
        const int j = pix - bb * 260;
        int h, w;
        if (j < 66)       { h = 0;  w = j; }
        else if (j < 132) { h = 65; w = j - 66; }
        else { int jj = j - 132; h = 1 + (jj & 63); w = (jj < 64) ? 0 : 65; }
        const uint4 z = {0u, 0u, 0u, 0u};
        *(uint4*)(Xp + ((size_t)((bb * HP_ + h) * HP_ + w) << 8) + chunk * 8) = z;
    }

    const int b  = bid >> 8;
    const int h  = (bid >> 2) & 63;
    const int cg = bid & 3;
    const int c0 = cg << 6;
    __shared__ float tile[64][65];
    {
        const int ci = tid >> 2, wseg = tid & 3;
        const float* src = x + ((size_t)(b * 256 + c0 + ci) << 12) + (h << 6) + wseg * 16;
        float s = 0.f;
#pragma unroll
        for (int i = 0; i < 4; ++i) {
            float4 v = *(const float4*)(src + i * 4);
            tile[ci][wseg * 16 + i * 4 + 0] = v.x;
            tile[ci][wseg * 16 + i * 4 + 1] = v.y;
            tile[ci][wseg * 16 + i * 4 + 2] = v.z;
            tile[ci][wseg * 16 + i * 4 + 3] = v.w;
            s += v.x + v.y + v.z + v.w;
        }
        // reduce the 4 wseg lanes (consecutive) and add to channel sum
        s += __shfl_down(s, 1, 64);
        s += __shfl_down(s, 2, 64);
        if ((tid & 3) == 0) atomicAdd(&xsum[b * 256 + c0 + ci], s);
    }
    __syncthreads();
    {
        const int w = tid >> 2, cs = tid & 3;
        unsigned short ov[16] __attribute__((aligned(16)));
#pragma unroll
        for (int k = 0; k < 16; ++k) ov[k] = f2bf(tile[cs * 16 + k][w]);
        unsigned short* dst = Xp + ((size_t)((b * HP_ + h + 1) * HP_ + (w + 1)) << 8) + c0 + cs * 16;
        ((uint4*)dst)[0] = ((const uint4*)ov)[0];
        ((uint4*)dst)[1] = ((const uint4*)ov)[1];
    }
}

// ---------- k_mix: mix[b][e] = softmax_e(dense(conv_w @ xmean + cb) + db) ----------
__global__ void k_mix(const float* __restrict__ xsum,
                      const float* __restrict__ cw, const float* __restrict__ cb,
                      const float* __restrict__ dw, const float* __restrict__ db,
                      float* __restrict__ mix) {
    const int b = blockIdx.x, tid = threadIdx.x;
    __shared__ __align__(16) float sxm[256];
    __shared__ __align__(16) float spool[256];
    __shared__ float sl[8];
    sxm[tid] = xsum[b * 256 + tid] * (1.0f / P_);
    __syncthreads();
    {
        float a = cb[tid];
        const float4* cwr = (const float4*)(cw + (size_t)tid * 256);
        const float4* xv4 = (const float4*)sxm;
#pragma unroll 8
        for (int c = 0; c < 64; ++c) {
            const float4 wv = cwr[c];
            const float4 xv = xv4[c];
            a += wv.x * xv.x + wv.y * xv.y + wv.z * xv.z + wv.w * xv.w;
        }
        spool[tid] = a;
    }
    __syncthreads();
    if (tid < 64) {
        const int e = tid >> 3, dl = tid & 7;
        float part = 0.f;
#pragma unroll 4
        for (int d = dl; d < 256; d += 8) part += dw[e * 256 + d] * spool[d];
        part += __shfl_down(part, 4, 64);
        part += __shfl_down(part, 2, 64);
        part += __shfl_down(part, 1, 64);
        if (dl == 0) sl[e] = part + db[e];
    }
    __syncthreads();
    if (tid < 8) {
        float m = sl[0];
        for (int e = 1; e < 8; ++e) m = fmaxf(m, sl[e]);
        float den = 0.f;
        for (int e = 0; e < 8; ++e) den += __expf(sl[e] - m);
        mix[b * 8 + tid] = __expf(sl[tid] - m) / den;
    }
}

// ---------- k_mixkern: Wg[b][o][t][ic] = bf16( sum_e mix[b][e] * KE[e][o][ic][t] ) ----------
__global__ void k_mixkern(const float* __restrict__ KE, const float* __restrict__ mix,
                          unsigned short* __restrict__ Wg) {
    const int o    = blockIdx.x >> 1;
    const int half = blockIdx.x & 1;
    const int ic0  = half << 7;
    const int tid  = threadIdx.x;
    __shared__ __align__(16) float s[8][1152];     // 36.9 KB
    __shared__ float smix[128];
    if (tid < 128) smix[tid] = mix[tid];
#pragma unroll
    for (int e = 0; e < 8; ++e) {
        const float4* src = (const float4*)(KE + (size_t)(e * 256 + o) * 2304 + ic0 * 9);
        float4* dst = (float4*)s[e];
        dst[tid] = src[tid];                         // float4 0..255
        if (tid < 32) dst[256 + tid] = src[256 + tid];  // float4 256..287 (= 1152 floats)
    }
    __syncthreads();
    const int icl = tid & 127;
    const int b0  = (tid >> 7) << 3;     // 0 or 8
#pragma unroll
    for (int t = 0; t < 9; ++t) {
        float v[8];
#pragma unroll
        for (int e = 0; e < 8; ++e) v[e] = s[e][icl * 9 + t];
#pragma unroll
        for (int bb = 0; bb < 8; ++bb) {
            const int b = b0 + bb;
            float acc = 0.f;
#pragma unroll
            for (int e = 0; e < 8; ++e) acc += smix[b * 8 + e] * v[e];
            Wg[((size_t)(b * 256 + o) * 9 + t) * 256 + ic0 + icl] = f2bf(acc);
        }
    }
}

// ---------- k_gemm: 256x256-tile 8-wave, interleaved-read 2-window GEMM ----------
// Round-8 change: break the LDS-pipe / MFMA-pipe serialization.
//  (a) setprio REMOVED everywhere — suspected LLVM scheduling fence that pinned
//      every ds_read burst outside every MFMA burst (rounds 4-7 all serialized:
//      window = LDS 2304 cyc + MFMA 2483 cyc = measured 4893).
//  (b) kk1's 12 fragment reads are hand-interleaved BETWEEN kk0's MFMA
//      half-blocks, reusing dead registers (af0/af1 reloaded after their last
//      kk0 use; bv kept live, bvn separate: +16 VGPR only — unified file
//      budget: ~124 VGPR + 128 acc AGPR < 256, no spill).
// Window = { 12 reads kk0; stage-issue; 16 MFMA(af0*bv); reload af0<-kk1 +
//            bvn<-kk1; 16 MFMA(af1*bv); reload af1<-kk1; 16 MFMA(af0*bvn);
//            16 MFMA(af1*bvn); vmcnt(0); s_barrier }.
// Only kk0's reads are exposed; kk1's drain under ~2000 cyc of MFMA.
// WAR on af reuse is compiler-managed (lgkmcnt + MFMA hazard rules).
// Slot ledger unchanged from round 7 (L0=A-even L1=A-odd L2=B-even L3=B-odd):
//   even window reads L0,L2, stages ->L1,L3; odd window reads L1,L3, stages
//   ->L0,L2 (pf-guarded); every window ends vmcnt(0)+s_barrier, so all reads
//   of a slot complete before any wave stages into it, and all stages land
//   before their consumer window starts.
__global__ __launch_bounds__(512, 2) void k_gemm(const unsigned short* __restrict__ Wg,
                                                 const unsigned short* __restrict__ Xp,
                                                 float* __restrict__ out) {
    __shared__ __align__(16) unsigned short L[4][16384];   // 128 KB
    const int tid = threadIdx.x;
    const int bid = blockIdx.x;
    const int xcd = bid & 7;
    const int g   = bid >> 3;            // 0..31
    const int b   = xcd + ((g >> 4) << 3);   // samples {xcd, xcd+8} share one XCD L2
    const int tile = g & 15;
    const int h0  = tile << 2;

    const int wid  = tid >> 6;           // 0..7
    const int lane = tid & 63;
    const int wm   = wid >> 2;           // 0..1: o-half (128 rows)
    const int wn   = wid & 3;            // 0..3: pixel row (64 pixels)
    const int ql   = lane & 15;
    const int quad = lane >> 4;
    const int sw   = ql & 7;             // read-side swizzle key (= row&7)

    const int srow = tid >> 3;           // 0..63
    const int csrc = (tid & 7) ^ (srow & 7);   // global chunk for this thread's LDS slot

    f32x4 acc[8][4];
#pragma unroll
    for (int i = 0; i < 8; ++i)
#pragma unroll
        for (int j = 0; j < 4; ++j) acc[i][j] = (f32x4)0.0f;

    // Stage full A-tile (256 o x 64 k) of K-tile s into L[P]. 4 x 16B per thread.
    auto stageA = [&](int s, int P) {
        const int t = s >> 2, kc = s & 3;
        const unsigned short* ga = Wg + ((size_t)(b * 256 + srow) * 9 + t) * 256
                                   + kc * 64 + csrc * 8;
#pragma unroll
        for (int j = 0; j < 4; ++j)
            async_load16(ga + (size_t)j * 64 * 9 * 256, (char*)L[P] + tid * 16 + j * 8192);
    };
    // Stage full B-tile (256 pixels x 64 k): row = srow + 64j -> pr=j, w=srow.
    auto stageB = [&](int s, int P) {
        const int t = s >> 2, kc = s & 3;
        const int kh = t / 3, kw = t - kh * 3;
#pragma unroll
        for (int j = 0; j < 4; ++j)
            async_load16(Xp + (((size_t)((b * HP_ + h0 + j + kh) * HP_ + (srow + kw))) << 8)
                             + kc * 64 + csrc * 8,
                         (char*)L[2 + P] + tid * 16 + j * 8192);
    };

    bf16x8 af0[4], af1[4], bv[4], bvn[4];

    // Fragment address helpers (swizzled).
#define AFADDR(AP, ROW, KK) ((const bf16x8*)((const char*)L[AP]                    \
        + (wm * 128 + (ROW) * 16 + ql) * 128 + (((((KK) << 2) | quad) ^ sw) << 4)))
#define BVADDR(BP, ROW, KK) ((const bf16x8*)((const char*)L[BP]                    \
        + (wn * 64 + (ROW) * 16 + ql) * 128 + (((((KK) << 2) | quad) ^ sw) << 4)))

#define RD_AF0(AP, KK) { _Pragma("unroll") for (int r_ = 0; r_ < 4; ++r_) af0[r_] = *AFADDR(AP, r_, KK); }
#define RD_AF1(AP, KK) { _Pragma("unroll") for (int r_ = 0; r_ < 4; ++r_) af1[r_] = *AFADDR(AP, 4 + r_, KK); }
#define RD_BV(BP, KK)  { _Pragma("unroll") for (int r_ = 0; r_ < 4; ++r_) bv[r_]  = *BVADDR(BP, r_, KK); }
#define RD_BVN(BP, KK) { _Pragma("unroll") for (int r_ = 0; r_ < 4; ++r_) bvn[r_] = *BVADDR(BP, r_, KK); }

#define MF16(AF, BB, MBASE)                                                        \
    { _Pragma("unroll")                                                            \
      for (int r_ = 0; r_ < 4; ++r_)                                               \
          _Pragma("unroll")                                                        \
          for (int n_ = 0; n_ < 4; ++n_)                                           \
              acc[(MBASE) + r_][n_] = __builtin_amdgcn_mfma_f32_16x16x32_bf16(     \
                  AF[r_], BB[n_], acc[(MBASE) + r_][n_], 0, 0, 0); }

    // One parity window: reads slots AP/BP; PREF_STMT issues next stages;
    // VM_STMT is the end-of-window vmcnt.
#define WINDOW(AP, BP, PREF_STMT, VM_STMT)                                         \
    do {                                                                           \
        RD_AF0(AP, 0); RD_AF1(AP, 0); RD_BV(BP, 0);   /* kk0: 12 reads */          \
        PREF_STMT;                                    /* 8 stage-issues */         \
        MF16(af0, bv, 0);                             /* 16 MFMA (af0 dead) */     \
        RD_AF0(AP, 1);                                /* af0 <- kk1 */             \
        RD_BVN(BP, 1);                                /* bvn <- kk1 */             \
        MF16(af1, bv, 4);                             /* 16 MFMA (af1,bv dead) */  \
        RD_AF1(AP, 1);                                /* af1 <- kk1 */             \
        MF16(af0, bvn, 0);                            /* 16 MFMA kk1 */            \
        MF16(af1, bvn, 4);                            /* 16 MFMA kk1 */            \
        VM_STMT;                                                                   \
        asm volatile("s_barrier" ::: "memory");                                    \
    } while (0)

    // Prologue: A(0)->L[0], B(0)->L[2]; drain; barrier.
    stageA(0, 0); stageB(0, 0);
    asm volatile("s_waitcnt vmcnt(0)" ::: "memory");
    asm volatile("s_barrier" ::: "memory");

    for (int i = 0; i < 18; ++i) {
        const int sE = 2 * i;
        const int sO = sE + 1;
        const bool pf = (i < 17);
        // even window: reads L0,L2; stages -> L1,L3
        WINDOW(0, 2,
               { stageA(sO, 1); stageB(sO, 1); },
               { asm volatile("s_waitcnt vmcnt(0)" ::: "memory"); });
        // odd window: reads L1,L3; stages -> L0,L2
        WINDOW(1, 3,
               if (pf) { stageA(sE + 2, 0); stageB(sE + 2, 0); },
               if (pf) { asm volatile("s_waitcnt vmcnt(0)" ::: "memory"); });
    }
#undef WINDOW
#undef MF16
#undef RD_AF0
#undef RD_AF1
#undef RD_BV
#undef RD_BVN
#undef AFADDR
#undef BVADDR

    // Epilogue: C/D layout col=lane&15 (pixel), row=quad*4+reg (o)
#pragma unroll
    for (int m = 0; m < 8; ++m) {
        const int mh = m >> 2, mr = m & 3;           // acc index -> o offset
        const int o = wm * 128 + mh * 64 + mr * 16 + quad * 4;
#pragma unroll
        for (int n = 0; n < 4; ++n) {
            const int w = n * 16 + ql;
            float* po = out + ((size_t)(b * 256 + o) << 12) + ((h0 + wn) << 6) + w;
#pragma unroll
            for (int r = 0; r < 4; ++r) po[(size_t)r << 12] = acc[mh * 4 + mr][n][r];
        }
    }
}

// ---------- launch ----------
extern "C" void kernel_launch(void* const* d_in, const int* in_sizes, int n_in,
                              void* d_out, int out_size, void* d_ws, size_t ws_size,
                              hipStream_t stream) {
    const float* x  = (const float*)d_in[0];
    const float* KE = (const float*)d_in[1];
    const float* cw = (const float*)d_in[2];
    const float* cb = (const float*)d_in[3];
    const float* dw = (const float*)d_in[4];
    const float* db = (const float*)d_in[5];
    float* out = (float*)d_out;

    char* ws = (char*)d_ws;
    float* xsum           = (float*)(ws + 0);            // 16*256*4    = 16 KB
    float* mix            = (float*)(ws + 16384);        // 16*8*4      = 512 B
    unsigned short* Wg    = (unsigned short*)(ws + 32768);            // 18.87 MB
    unsigned short* Xp    = (unsigned short*)(ws + 32768 + 18874368); // 35.68 MB

    hipMemsetAsync(xsum, 0, B_ * C_ * sizeof(float), stream);
    k_xpose  <<<dim3(B_ * H_ * 4),    dim3(256), 0, stream>>>(x, Xp, xsum);
    k_mix    <<<dim3(B_),             dim3(256), 0, stream>>>(xsum, cw, cb, dw, db, mix);
    k_mixkern<<<dim3(C_ * 2),         dim3(256), 0, stream>>>(KE, mix, Wg);
    k_gemm   <<<dim3(256),            dim3(512), 0, stream>>>(Wg, Xp, out);
}